// Round 5
// baseline (106.079 us; speedup 1.0000x reference)
//
#include <hip/hip_runtime.h>

namespace {

constexpr int B = 4, S = 4096, H = 16, D = 32;
constexpr int L = 32;             // chunk length
constexpr int NC = S / L;         // 128 chunks per sequence
constexpr int NBH = B * H;        // 64
constexpr int RS = H * D;         // 512 floats between consecutive time steps
constexpr int PW = 36;            // padded LDS row width (float4-aligned, conflict-free)
constexpr float GEPS = 1.52587890625e-05f;  // 2^-16 per-step decay clamp
                                            // (7 steps * 16 = 112 < 126)

__device__ __forceinline__ float flog2(float x) { return __builtin_amdgcn_logf(x); }
__device__ __forceinline__ float fexp2(float x) { return __builtin_amdgcn_exp2f(x); }

__device__ __forceinline__ float4 shflup4(float4 v, int d) {
    float4 r;
    r.x = __shfl_up(v.x, d, 64);
    r.y = __shfl_up(v.y, d, 64);
    r.z = __shfl_up(v.z, d, 64);
    r.w = __shfl_up(v.w, d, 64);
    return r;
}

// ---------------- Kernel 1: per-chunk summaries ----------------
// l = cumsum log2(max(g,GEPS)); W_j[m] = v_j[m]*2^{l_end[m]-l_j[m]} (<=1)
// KVb[bh][c][d][m] = sum_j k_j[d]*W_j[m];  Gb[bh][c][m] = 2^{l_end[m]}
__global__ __launch_bounds__(256)
void k1_chunk_summary(const float* __restrict__ Kp, const float* __restrict__ Vp,
                      const float* __restrict__ Gp, float* __restrict__ KVb,
                      float* __restrict__ Gb)
{
    __shared__ float k_s[L][PW];
    __shared__ float w_s[L][PW];
    __shared__ float tot[4][PW];

    const int blk = blockIdx.x;
    const int bh = blk / NC, c = blk % NC;
    const int b = bh / H, h = bh % H;
    const long base = ((long)b * S + (long)c * L) * RS + h * D;

    const int tid = threadIdx.x;
    const int i = tid >> 3;          // row 0..31
    const int u = (tid & 7) * 4;     // col quad
    const int wv = tid >> 6;         // wave id == sub-block id
    const int rw = i & 7;            // row within wave
    const long roff = base + (long)i * RS + u;

    float4 k4 = *(const float4*)(Kp + roff);
    float4 v4 = *(const float4*)(Vp + roff);
    float4 g4 = *(const float4*)(Gp + roff);
    *(float4*)&k_s[i][u] = k4;

    float4 val;
    val.x = flog2(fmaxf(g4.x, GEPS));
    val.y = flog2(fmaxf(g4.y, GEPS));
    val.z = flog2(fmaxf(g4.z, GEPS));
    val.w = flog2(fmaxf(g4.w, GEPS));

    // wave-local inclusive scan over 8 rows (lane offsets 8/16/32)
    float4 t;
    t = shflup4(val, 8);
    if (rw >= 1) { val.x += t.x; val.y += t.y; val.z += t.z; val.w += t.w; }
    t = shflup4(val, 16);
    if (rw >= 2) { val.x += t.x; val.y += t.y; val.z += t.z; val.w += t.w; }
    t = shflup4(val, 32);
    if (rw >= 4) { val.x += t.x; val.y += t.y; val.z += t.z; val.w += t.w; }
    if (rw == 7) *(float4*)&tot[wv][u] = val;
    __syncthreads();

    float4 run = {0, 0, 0, 0}, eall = {0, 0, 0, 0};
    #pragma unroll
    for (int s2 = 0; s2 < 4; ++s2) {
        float4 tt = *(float4*)&tot[s2][u];
        eall.x += tt.x; eall.y += tt.y; eall.z += tt.z; eall.w += tt.w;
        if (s2 < wv) { run.x += tt.x; run.y += tt.y; run.z += tt.z; run.w += tt.w; }
    }
    val.x += run.x; val.y += run.y; val.z += run.z; val.w += run.w;  // final l_i

    float4 w4;
    w4.x = v4.x * fexp2(eall.x - val.x);
    w4.y = v4.y * fexp2(eall.y - val.y);
    w4.z = v4.z * fexp2(eall.z - val.z);
    w4.w = v4.w * fexp2(eall.w - val.w);
    *(float4*)&w_s[i][u] = w4;

    if (i == 0) {
        float4 gg;
        gg.x = fexp2(eall.x); gg.y = fexp2(eall.y);
        gg.z = fexp2(eall.z); gg.w = fexp2(eall.w);
        *(float4*)(Gb + (long)(bh * NC + c) * D + u) = gg;
    }
    __syncthreads();

    // KV[d][m] = sum_j k[j][d] * W[j][m]
    const int d = tid >> 3;
    const int mg = (tid & 7) * 4;
    float4 acc = {0, 0, 0, 0};
    #pragma unroll
    for (int j = 0; j < L; ++j) {
        float kv = k_s[j][d];
        float4 w = *(float4*)&w_s[j][mg];
        acc.x += kv * w.x; acc.y += kv * w.y; acc.z += kv * w.z; acc.w += kv * w.w;
    }
    *(float4*)(KVb + (long)(bh * NC + c) * (D * D) + d * D + mg) = acc;
}

// ---------------- Kernel 2: inter-chunk scan (in-place KV -> S0) ----------------
// 8-deep double-buffered prefetch; all register indices static.
__global__ __launch_bounds__(256)
void k2_scan(float* __restrict__ KVb, const float* __restrict__ Gb)
{
    const int bh = blockIdx.x >> 2;
    const int dg = blockIdx.x & 3;
    const int tid = threadIdx.x;
    const int d = dg * 8 + (tid >> 5);
    const int m = tid & 31;

    const long kvoff = (long)bh * NC * (D * D) + d * D + m;
    const long goff = (long)bh * NC * D + m;

    float ka[8], ga[8];
    #pragma unroll
    for (int t = 0; t < 8; ++t) {
        ka[t] = KVb[kvoff + (long)t * (D * D)];
        ga[t] = Gb[goff + (long)t * D];
    }
    float st = 0.f;
    for (int c0 = 0; c0 < NC; c0 += 8) {
        float kb[8], gb2[8];
        const bool more = (c0 + 8) < NC;
        #pragma unroll
        for (int t = 0; t < 8; ++t) {
            kb[t]  = more ? KVb[kvoff + (long)(c0 + 8 + t) * (D * D)] : 0.f;
            gb2[t] = more ? Gb[goff + (long)(c0 + 8 + t) * D] : 0.f;
        }
        #pragma unroll
        for (int t = 0; t < 8; ++t) {
            KVb[kvoff + (long)(c0 + t) * (D * D)] = st;   // chunk-START state
            st = ga[t] * st + ka[t];
        }
        #pragma unroll
        for (int t = 0; t < 8; ++t) { ka[t] = kb[t]; ga[t] = gb2[t]; }
    }
}

// ---------------- Kernel 3: per-chunk outputs ----------------
// out_i[m] = 2^{l_i[m]}*(q_i.S0[:,m])
//          + sum_{s<=si} 2^{l_i[m]-e_s[m]} * sum_{j in s, j<=i} A_ij*W_j[m]
// W_j[m] = v_j[m]*2^{e_{s(j)}[m]-l_j[m]};  e_s from running sum of wave totals.
__global__ __launch_bounds__(256)
void k3_out(const float* __restrict__ Qp, const float* __restrict__ Kp,
            const float* __restrict__ Vp, const float* __restrict__ Gp,
            const float* __restrict__ S0b, float* __restrict__ Op)
{
    __shared__ float q_s[L][PW];
    __shared__ float kT[D][L + 1];
    __shared__ float w_s[L][PW];
    __shared__ float s0_s[D][PW];
    __shared__ float a_s[L][L + 1];
    __shared__ float tot[4][PW];

    const int blk = blockIdx.x;
    const int bh = blk / NC, c = blk % NC;
    const int b = bh / H, h = bh % H;
    const long base = ((long)b * S + (long)c * L) * RS + h * D;

    const int tid = threadIdx.x;
    const int i = tid >> 3;
    const int u = (tid & 7) * 4;
    const int wv = tid >> 6;         // wave id == sub-block si
    const int rw = i & 7;
    const long roff = base + (long)i * RS + u;

    float4 q4 = *(const float4*)(Qp + roff);
    float4 k4 = *(const float4*)(Kp + roff);
    float4 v4 = *(const float4*)(Vp + roff);
    float4 g4 = *(const float4*)(Gp + roff);
    float4 s04 = *(const float4*)(S0b + (long)(bh * NC + c) * (D * D) + tid * 4);

    *(float4*)&q_s[i][u] = q4;
    kT[u + 0][i] = k4.x; kT[u + 1][i] = k4.y;
    kT[u + 2][i] = k4.z; kT[u + 3][i] = k4.w;
    *(float4*)&s0_s[tid >> 3][(tid & 7) * 4] = s04;

    float4 val;
    val.x = flog2(fmaxf(g4.x, GEPS));
    val.y = flog2(fmaxf(g4.y, GEPS));
    val.z = flog2(fmaxf(g4.z, GEPS));
    val.w = flog2(fmaxf(g4.w, GEPS));

    float4 t;
    t = shflup4(val, 8);
    if (rw >= 1) { val.x += t.x; val.y += t.y; val.z += t.z; val.w += t.w; }
    t = shflup4(val, 16);
    if (rw >= 2) { val.x += t.x; val.y += t.y; val.z += t.z; val.w += t.w; }
    t = shflup4(val, 32);
    if (rw >= 4) { val.x += t.x; val.y += t.y; val.z += t.z; val.w += t.w; }
    if (rw == 7) *(float4*)&tot[wv][u] = val;
    __syncthreads();   // barrier 1: q_s, kT, s0_s, tot visible

    float4 run = {0, 0, 0, 0};
    #pragma unroll
    for (int s2 = 0; s2 < 4; ++s2) {
        if (s2 < wv) {
            float4 tt = *(float4*)&tot[s2][u];
            run.x += tt.x; run.y += tt.y; run.z += tt.z; run.w += tt.w;
        }
    }
    val.x += run.x; val.y += run.y; val.z += run.z; val.w += run.w;  // final l_i
    float4 ew = *(float4*)&tot[wv][u];   // own-wave total (dynamic LDS row: fine)
    float4 esi;                          // e_{si} = run + tot[wv]
    esi.x = run.x + ew.x; esi.y = run.y + ew.y;
    esi.z = run.z + ew.z; esi.w = run.w + ew.w;

    // W_j = v_j * 2^{e_{s(j)} - l_j}   (exponent <= 0)
    {
        float4 w4;
        w4.x = v4.x * fexp2(esi.x - val.x);
        w4.y = v4.y * fexp2(esi.y - val.y);
        w4.z = v4.z * fexp2(esi.z - val.z);
        w4.w = v4.w * fexp2(esi.w - val.w);
        *(float4*)&w_s[i][u] = w4;
    }

    // own q row into registers
    float4 tq[8];
    #pragma unroll
    for (int dd = 0; dd < 8; ++dd) tq[dd] = *(float4*)&q_s[i][dd * 4];

    // A[i][u..u+3] = q_i . k_j  (unmasked; consumers use j<=i only)
    {
        float4 a = {0, 0, 0, 0};
        #pragma unroll
        for (int dd = 0; dd < 8; ++dd) {
            #pragma unroll
            for (int cc = 0; cc < 4; ++cc) {
                const float qv = (&tq[dd].x)[cc];
                const int d = dd * 4 + cc;
                a.x += qv * kT[d][u + 0];
                a.y += qv * kT[d][u + 1];
                a.z += qv * kT[d][u + 2];
                a.w += qv * kT[d][u + 3];
            }
        }
        a_s[i][u + 0] = a.x; a_s[i][u + 1] = a.y;
        a_s[i][u + 2] = a.z; a_s[i][u + 3] = a.w;
    }
    __syncthreads();   // barrier 2: w_s, a_s visible

    // cross-chunk term: 2^{l_i} * (q_i . S0[:,m])
    float4 o = {0, 0, 0, 0};
    #pragma unroll
    for (int dd = 0; dd < 8; ++dd) {
        #pragma unroll
        for (int cc = 0; cc < 4; ++cc) {
            const float qv = (&tq[dd].x)[cc];
            float4 s4 = *(float4*)&s0_s[dd * 4 + cc][u];
            o.x += qv * s4.x; o.y += qv * s4.y; o.z += qv * s4.z; o.w += qv * s4.w;
        }
    }
    o.x *= fexp2(val.x); o.y *= fexp2(val.y);
    o.z *= fexp2(val.z); o.w *= fexp2(val.w);

    // intra-chunk, sub-block factorized; e_s rebuilt as running sum of tot rows
    float4 run2 = {0, 0, 0, 0};
    #pragma unroll
    for (int s2 = 0; s2 < 4; ++s2) {
        if (s2 <= wv) {
            float4 tt = *(float4*)&tot[s2][u];
            run2.x += tt.x; run2.y += tt.y; run2.z += tt.z; run2.w += tt.w;
            float4 tc = {0, 0, 0, 0};
            if (s2 < wv) {
                #pragma unroll
                for (int jj = 0; jj < 8; ++jj) {
                    const float av = a_s[i][s2 * 8 + jj];
                    float4 w = *(float4*)&w_s[s2 * 8 + jj][u];
                    tc.x += av * w.x; tc.y += av * w.y;
                    tc.z += av * w.z; tc.w += av * w.w;
                }
            } else {
                #pragma unroll
                for (int jj = 0; jj < 8; ++jj) {
                    const int j = s2 * 8 + jj;
                    const float av = (j <= i) ? a_s[i][j] : 0.f;
                    float4 w = *(float4*)&w_s[j][u];
                    tc.x += av * w.x; tc.y += av * w.y;
                    tc.z += av * w.z; tc.w += av * w.w;
                }
            }
            // s2<wv: exponent <= 0; s2==wv: in [0,112] -> finite
            o.x += fexp2(val.x - run2.x) * tc.x;
            o.y += fexp2(val.y - run2.y) * tc.y;
            o.z += fexp2(val.z - run2.z) * tc.z;
            o.w += fexp2(val.w - run2.w) * tc.w;
        }
    }

    *(float4*)(Op + roff) = o;
}

} // namespace

extern "C" void kernel_launch(void* const* d_in, const int* in_sizes, int n_in,
                              void* d_out, int out_size, void* d_ws, size_t ws_size,
                              hipStream_t stream)
{
    const float* q = (const float*)d_in[0];
    const float* k = (const float*)d_in[1];
    const float* v = (const float*)d_in[2];
    const float* g = (const float*)d_in[3];
    float* out = (float*)d_out;

    float* KVb = (float*)d_ws;                       // [NBH][NC][D][D]  (33.55 MB)
    float* Gb = KVb + (long)NBH * NC * D * D;        // [NBH][NC][D]     (1.05 MB)

    dim3 blk(256);
    k1_chunk_summary<<<dim3(NBH * NC), blk, 0, stream>>>(k, v, g, KVb, Gb);
    k2_scan<<<dim3(NBH * 4), blk, 0, stream>>>(KVb, Gb);
    k3_out<<<dim3(NBH * NC), blk, 0, stream>>>(q, k, v, g, KVb, out);
}